// Round 8
// baseline (598.857 us; speedup 1.0000x reference)
//
#include <hip/hip_runtime.h>
#include <math.h>

#define H 1024
#define V 50257
#define L 18
#define NBLK 512            // 2 blocks/CU on 256 CUs -> co-residency guaranteed
#define NWAVE 2048          // NBLK * 4 waves

// ws layout (floats):
//   [0, 2048)      cat2 = [embedded | attn_applied]
//   [2080, 3104)   x  (combine+relu output)
//   [3104, 6176)   gh (Whh·h + bhh, 3H)
//   [6176, 7200)   h_new
//   [7200, 11296)  per-wave (m, s) pairs (2048 x 2)
//   [11296, ...)   barrier state (8 unsigned), zeroed by k_front each call
#define WS_CAT   0
#define WS_X     2080
#define WS_GH    3104
#define WS_HNEW  6176
#define WS_PAIRS 7200
#define WS_BAR   11296

__device__ __forceinline__ float waveReduceSum(float v) {
#pragma unroll
    for (int off = 32; off > 0; off >>= 1) v += __shfl_xor(v, off);
    return v;
}

// Device-scope grid barrier. Safe because all NBLK blocks are co-resident
// (2 blocks/CU, __launch_bounds__(256,2) caps VGPR at 256). State zeroed by
// the preceding kernel on the same stream.
__device__ __forceinline__ void gbar(unsigned* bar, int id, unsigned nblk) {
    __syncthreads();
    if (threadIdx.x == 0) {
        unsigned* cnt  = bar + 2 * id;
        unsigned* flag = bar + 2 * id + 1;
        __threadfence();                         // release this block's writes
        if (atomicAdd(cnt, 1u) == nblk - 1u) {
            __hip_atomic_store(flag, 1u, __ATOMIC_RELEASE, __HIP_MEMORY_SCOPE_AGENT);
        } else {
            while (__hip_atomic_load(flag, __ATOMIC_ACQUIRE, __HIP_MEMORY_SCOPE_AGENT) == 0u)
                __builtin_amdgcn_s_sleep(8);
        }
        __threadfence();                         // acquire other blocks' writes
    }
    __syncthreads();
}

// ---------------- k_front: barrier init + embedding + attention + attn_applied
__global__ __launch_bounds__(1024) void k_front(
    const int* __restrict__ ids, const float* __restrict__ hidden,
    const float* __restrict__ enc, const float* __restrict__ emb,
    const float* __restrict__ attn_W, const float* __restrict__ attn_b,
    float* __restrict__ ws, float* __restrict__ out)
{
    __shared__ float s_scores[32];
    __shared__ float s_w[L];
    const int t = threadIdx.x;
    const int wave = t >> 6, lane = t & 63;

    if (t < 8) ((unsigned*)(ws + WS_BAR))[t] = 0u;   // zero barrier state

    const int id = ids[0];
    const float* erow = emb + (size_t)id * H;

    ws[WS_CAT + t] = erow[t];                        // embedded -> cat2[0:H]

    const float4* e4 = (const float4*)erow;
    const float4* h4 = (const float4*)hidden;
    float4 ereg[4], hreg[4];
#pragma unroll
    for (int k = 0; k < 4; ++k) { ereg[k] = e4[lane + k * 64]; hreg[k] = h4[lane + k * 64]; }

    for (int l = wave; l < L; l += 16) {
        const float4* r4 = (const float4*)(attn_W + (size_t)l * 2 * H);
        float acc = 0.f;
#pragma unroll
        for (int k = 0; k < 4; ++k) {
            float4 a = r4[lane + k * 64];
            acc += a.x * ereg[k].x + a.y * ereg[k].y + a.z * ereg[k].z + a.w * ereg[k].w;
        }
#pragma unroll
        for (int k = 0; k < 4; ++k) {
            float4 a = r4[256 + lane + k * 64];
            acc += a.x * hreg[k].x + a.y * hreg[k].y + a.z * hreg[k].z + a.w * hreg[k].w;
        }
        acc = waveReduceSum(acc);
        if (lane == 0) s_scores[l] = acc + attn_b[l];
    }
    __syncthreads();

    if (wave == 0) {
        float v = (lane < L) ? s_scores[lane] : -INFINITY;
        float m = v;
#pragma unroll
        for (int off = 32; off > 0; off >>= 1) m = fmaxf(m, __shfl_xor(m, off));
        float e = (lane < L) ? expf(v - m) : 0.f;
        float s = waveReduceSum(e);
        float w = e / s;
        if (lane < L) {
            s_w[lane] = w;
            out[(size_t)V + H + lane] = w;           // attn_weights output
        }
    }
    __syncthreads();

    {   // attn_applied[i] = sum_l w[l] * enc[l][i]
        float acc = 0.f;
#pragma unroll
        for (int l = 0; l < L; ++l) acc += s_w[l] * enc[l * H + t];
        ws[WS_CAT + H + t] = acc;
    }
}

// ---------------- k_big: [comb + Whh] -> bar -> [GRU] -> bar -> [vocab GEMV] -> bar -> [lse+sub]
__global__ __launch_bounds__(256, 2) void k_big(
    const float* __restrict__ hidden,
    const float* __restrict__ comb_W, const float* __restrict__ comb_b,
    const float* __restrict__ Whh, const float* __restrict__ bhh,
    const float* __restrict__ Wih, const float* __restrict__ bih,
    const float* __restrict__ out_W, const float* __restrict__ out_b,
    float* __restrict__ ws, float* __restrict__ out)
{
    __shared__ float s_a[256], s_b[256];
    unsigned* bar = (unsigned*)(ws + WS_BAR);
    const int t = threadIdx.x;
    const int wid = t >> 6, lane = t & 63;
    const int W = blockIdx.x * 4 + wid;              // wave id in [0, 2048)

    const float4* h4 = (const float4*)hidden;
    float4 hreg[4];
#pragma unroll
    for (int k = 0; k < 4; ++k) hreg[k] = h4[lane + k * 64];

    // ---- Phase A: comb rows (W<1024) or Whh row W-1024; plus Whh row W+1024
    if (W < 1024) {
        const float4* c4 = (const float4*)(ws + WS_CAT);
        float4 creg[8];
#pragma unroll
        for (int k = 0; k < 8; ++k) creg[k] = c4[lane + k * 64];
        const float4* r4 = (const float4*)(comb_W + (size_t)W * 2 * H);
        float acc = 0.f;
#pragma unroll
        for (int k = 0; k < 8; ++k) {
            float4 a = r4[lane + k * 64];
            acc += a.x * creg[k].x + a.y * creg[k].y + a.z * creg[k].z + a.w * creg[k].w;
        }
        acc = waveReduceSum(acc);
        if (lane == 0) ws[WS_X + W] = fmaxf(acc + comb_b[W], 0.f);
    } else {
        const int r2 = W - 1024;                     // Whh rows [0,1024)
        const float4* r4 = (const float4*)(Whh + (size_t)r2 * H);
        float acc = 0.f;
#pragma unroll
        for (int k = 0; k < 4; ++k) {
            float4 a = r4[lane + k * 64];
            acc += a.x * hreg[k].x + a.y * hreg[k].y + a.z * hreg[k].z + a.w * hreg[k].w;
        }
        acc = waveReduceSum(acc);
        if (lane == 0) ws[WS_GH + r2] = acc + bhh[r2];
    }
    {
        const int r3 = W + 1024;                     // Whh rows [1024,3072)
        const float4* r4 = (const float4*)(Whh + (size_t)r3 * H);
        float acc = 0.f;
#pragma unroll
        for (int k = 0; k < 4; ++k) {
            float4 a = r4[lane + k * 64];
            acc += a.x * hreg[k].x + a.y * hreg[k].y + a.z * hreg[k].z + a.w * hreg[k].w;
        }
        acc = waveReduceSum(acc);
        if (lane == 0) ws[WS_GH + r3] = acc + bhh[r3];
    }
    gbar(bar, 0, NBLK);

    // ---- Phase B: GRU for j = W (waves < 1024)
    if (W < H) {
        const float4* x4 = (const float4*)(ws + WS_X);
        float4 xreg[4];
#pragma unroll
        for (int k = 0; k < 4; ++k) xreg[k] = x4[lane + k * 64];
        float d[3];
#pragma unroll
        for (int g = 0; g < 3; ++g) {
            const float4* r4 = (const float4*)(Wih + (size_t)(g * H + W) * H);
            float acc = 0.f;
#pragma unroll
            for (int k = 0; k < 4; ++k) {
                float4 a = r4[lane + k * 64];
                acc += a.x * xreg[k].x + a.y * xreg[k].y + a.z * xreg[k].z + a.w * xreg[k].w;
            }
            d[g] = waveReduceSum(acc);
        }
        if (lane == 0) {
            float i_r = d[0] + bih[W];
            float i_z = d[1] + bih[H + W];
            float i_n = d[2] + bih[2 * H + W];
            float h_r = ws[WS_GH + W];
            float h_z = ws[WS_GH + H + W];
            float h_n = ws[WS_GH + 2 * H + W];
            float hj  = hidden[W];
            float rg = 1.f / (1.f + expf(-(i_r + h_r)));
            float zg = 1.f / (1.f + expf(-(i_z + h_z)));
            float ng = tanhf(i_n + rg * h_n);
            float hn = (1.f - zg) * ng + zg * hj;
            ws[WS_HNEW + W] = hn;
            out[(size_t)V + W] = hn;                 // h_new output
        }
    }
    gbar(bar, 1, NBLK);

    // ---- Phase C: logits (2 rows per iteration) + per-wave online (m,s)
    const float4* n4 = (const float4*)(ws + WS_HNEW);
    float4 nreg[4];
#pragma unroll
    for (int k = 0; k < 4; ++k) nreg[k] = n4[lane + k * 64];

    float m = -INFINITY, s = 0.f;
    for (int v = W * 2; v < V; v += NWAVE * 2) {
        const int v1 = v + 1;
        const float4* r4a = (const float4*)(out_W + (size_t)v * H);
        float acc0 = 0.f, acc1 = 0.f;
        if (v1 < V) {
            const float4* r4b = (const float4*)(out_W + (size_t)v1 * H);
#pragma unroll
            for (int k = 0; k < 4; ++k) {
                float4 a = r4a[lane + k * 64];
                float4 b = r4b[lane + k * 64];
                acc0 += a.x * nreg[k].x + a.y * nreg[k].y + a.z * nreg[k].z + a.w * nreg[k].w;
                acc1 += b.x * nreg[k].x + b.y * nreg[k].y + b.z * nreg[k].z + b.w * nreg[k].w;
            }
        } else {
#pragma unroll
            for (int k = 0; k < 4; ++k) {
                float4 a = r4a[lane + k * 64];
                acc0 += a.x * nreg[k].x + a.y * nreg[k].y + a.z * nreg[k].z + a.w * nreg[k].w;
            }
        }
        acc0 = waveReduceSum(acc0);
        acc1 = waveReduceSum(acc1);
        float logit0 = acc0 + out_b[v];
        if (lane == 0) out[v] = logit0;
        float mn = fmaxf(m, logit0);
        s = s * expf(m - mn) + expf(logit0 - mn);
        m = mn;
        if (v1 < V) {
            float logit1 = acc1 + out_b[v1];
            if (lane == 0) out[v1] = logit1;
            mn = fmaxf(m, logit1);
            s = s * expf(m - mn) + expf(logit1 - mn);
            m = mn;
        }
    }
    if (lane == 0) {
        ws[WS_PAIRS + W * 2]     = m;
        ws[WS_PAIRS + W * 2 + 1] = s;
    }
    gbar(bar, 2, NBLK);

    // ---- Phase D: every block redundantly reduces 2048 pairs -> lse; subtract own chunk
    float M = -INFINITY, S = 0.f;
    for (int i = t; i < NWAVE; i += 256) {
        float m2 = ws[WS_PAIRS + i * 2], s2 = ws[WS_PAIRS + i * 2 + 1];
        float Mn = fmaxf(M, m2);
        S = S * expf(M - Mn) + s2 * expf(m2 - Mn);
        M = Mn;
    }
    s_a[t] = M; s_b[t] = S;
    __syncthreads();
    for (int off = 128; off > 0; off >>= 1) {
        if (t < off) {
            float m2 = s_a[t + off], s2 = s_b[t + off];
            float Mn = fmaxf(s_a[t], m2);
            s_b[t] = s_b[t] * expf(s_a[t] - Mn) + s2 * expf(m2 - Mn);
            s_a[t] = Mn;
        }
        __syncthreads();
    }
    const float lse = s_a[0] + logf(s_b[0]);
    for (int v = blockIdx.x * 256 + t; v < V; v += NBLK * 256) out[v] -= lse;
}

extern "C" void kernel_launch(void* const* d_in, const int* in_sizes, int n_in,
                              void* d_out, int out_size, void* d_ws, size_t ws_size,
                              hipStream_t stream) {
    const int*   ids    = (const int*)  d_in[0];
    const float* hidden = (const float*)d_in[1];
    const float* enc    = (const float*)d_in[2];
    const float* emb    = (const float*)d_in[3];
    const float* attn_W = (const float*)d_in[4];
    const float* attn_b = (const float*)d_in[5];
    const float* comb_W = (const float*)d_in[6];
    const float* comb_b = (const float*)d_in[7];
    const float* Wih    = (const float*)d_in[8];
    const float* Whh    = (const float*)d_in[9];
    const float* bih    = (const float*)d_in[10];
    const float* bhh    = (const float*)d_in[11];
    const float* out_W  = (const float*)d_in[12];
    const float* out_b  = (const float*)d_in[13];
    float* out = (float*)d_out;
    float* ws  = (float*)d_ws;

    hipLaunchKernelGGL(k_front, dim3(1),    dim3(1024), 0, stream,
                       ids, hidden, enc, emb, attn_W, attn_b, ws, out);
    hipLaunchKernelGGL(k_big,   dim3(NBLK), dim3(256),  0, stream,
                       hidden, comb_W, comb_b, Whh, bhh, Wih, bih,
                       out_W, out_b, ws, out);
}

// Round 10
// 422.673 us; speedup vs baseline: 1.4168x; 1.4168x over previous
//
#include <hip/hip_runtime.h>
#include <math.h>

#define H 1024
#define V 50257
#define L 18

// ws layout (floats):
//   [0, 1024)      embedded
//   [1024, 2048)   attn_applied   (together: cat2 = [embedded | attn_applied])
//   [2080, 3104)   x  (combine+relu output)
//   [3104, 6176)   gh (Whh·h + bhh, 3H)
//   [6176, 7200)   h_new
//   [7200, 11296)  per-block (m, s) pairs from k4 (2048 blocks × 2)
#define WS_CAT   0
#define WS_X     2080
#define WS_GH    3104
#define WS_HNEW  6176
#define WS_PAIRS 7200
#define NBLK4    2048   // 8 blocks/CU × 256 thr = 32 waves/CU (HW max)

__device__ __forceinline__ float waveReduceSum(float v) {
#pragma unroll
    for (int off = 32; off > 0; off >>= 1) v += __shfl_xor(v, off);
    return v;
}

// ---------------- k1: embedding + attention scores + softmax + attn_applied
// 1024 threads: one pass over H, 16 waves cover the 18 score rows.
__global__ __launch_bounds__(1024) void k1_attn(
    const int* __restrict__ ids, const float* __restrict__ hidden,
    const float* __restrict__ enc, const float* __restrict__ emb,
    const float* __restrict__ attn_W, const float* __restrict__ attn_b,
    float* __restrict__ ws, float* __restrict__ out)
{
    __shared__ float s_scores[32];
    __shared__ float s_w[L];
    const int t = threadIdx.x;
    const int wave = t >> 6, lane = t & 63;
    const int id = ids[0];
    const float* erow = emb + (size_t)id * H;

    ws[WS_CAT + t] = erow[t];                        // embedded -> cat2[0:H]

    const float4* e4 = (const float4*)erow;
    const float4* h4 = (const float4*)hidden;
    float4 ereg[4], hreg[4];
#pragma unroll
    for (int k = 0; k < 4; ++k) { ereg[k] = e4[lane + k * 64]; hreg[k] = h4[lane + k * 64]; }

    for (int l = wave; l < L; l += 16) {
        const float4* r4 = (const float4*)(attn_W + (size_t)l * 2 * H);
        float acc = 0.f;
#pragma unroll
        for (int k = 0; k < 4; ++k) {
            float4 a = r4[lane + k * 64];          // vs embedded
            acc += a.x * ereg[k].x + a.y * ereg[k].y + a.z * ereg[k].z + a.w * ereg[k].w;
        }
#pragma unroll
        for (int k = 0; k < 4; ++k) {
            float4 a = r4[256 + lane + k * 64];    // vs hidden
            acc += a.x * hreg[k].x + a.y * hreg[k].y + a.z * hreg[k].z + a.w * hreg[k].w;
        }
        acc = waveReduceSum(acc);
        if (lane == 0) s_scores[l] = acc + attn_b[l];
    }
    __syncthreads();

    if (wave == 0) {
        float v = (lane < L) ? s_scores[lane] : -INFINITY;
        float m = v;
#pragma unroll
        for (int off = 32; off > 0; off >>= 1) m = fmaxf(m, __shfl_xor(m, off));
        float e = (lane < L) ? expf(v - m) : 0.f;
        float s = waveReduceSum(e);
        float w = e / s;
        if (lane < L) {
            s_w[lane] = w;
            out[(size_t)V + H + lane] = w;   // attn_weights output
        }
    }
    __syncthreads();

    {   // attn_applied[i] = sum_l w[l] * enc[l][i]
        float acc = 0.f;
#pragma unroll
        for (int l = 0; l < L; ++l) acc += s_w[l] * enc[l * H + t];
        ws[WS_CAT + H + t] = acc;
    }
}

// ---------------- k2: x = relu(comb_W·cat2 + comb_b)  AND  gh = Whh·h + bhh
__global__ __launch_bounds__(256) void k2_comb_gh(
    const float* __restrict__ hidden,
    const float* __restrict__ comb_W, const float* __restrict__ comb_b,
    const float* __restrict__ Whh, const float* __restrict__ bhh,
    float* __restrict__ ws)
{
    const int t = threadIdx.x;
    const int wave = t >> 6, lane = t & 63;
    const int r = blockIdx.x * 4 + wave;          // 0..4095

    if (r < H) {
        const float4* c4 = (const float4*)(ws + WS_CAT);
        float4 creg[8];
#pragma unroll
        for (int k = 0; k < 8; ++k) creg[k] = c4[lane + k * 64];
        const float4* r4 = (const float4*)(comb_W + (size_t)r * 2 * H);
        float acc = 0.f;
#pragma unroll
        for (int k = 0; k < 8; ++k) {
            float4 a = r4[lane + k * 64];
            acc += a.x * creg[k].x + a.y * creg[k].y + a.z * creg[k].z + a.w * creg[k].w;
        }
        acc = waveReduceSum(acc);
        if (lane == 0) ws[WS_X + r] = fmaxf(acc + comb_b[r], 0.f);
    } else {
        const int r2 = r - H;                      // 0..3071
        const float4* h4 = (const float4*)hidden;
        float4 hreg[4];
#pragma unroll
        for (int k = 0; k < 4; ++k) hreg[k] = h4[lane + k * 64];
        const float4* r4 = (const float4*)(Whh + (size_t)r2 * H);
        float acc = 0.f;
#pragma unroll
        for (int k = 0; k < 4; ++k) {
            float4 a = r4[lane + k * 64];
            acc += a.x * hreg[k].x + a.y * hreg[k].y + a.z * hreg[k].z + a.w * hreg[k].w;
        }
        acc = waveReduceSum(acc);
        if (lane == 0) ws[WS_GH + r2] = acc + bhh[r2];
    }
}

// ---------------- k3: gi = Wih·x + bih (3 rows per wave) + GRU gates -> h_new
__global__ __launch_bounds__(256) void k3_gru(
    const float* __restrict__ hidden,
    const float* __restrict__ Wih, const float* __restrict__ bih,
    float* __restrict__ ws, float* __restrict__ out)
{
    const int t = threadIdx.x;
    const int wave = t >> 6, lane = t & 63;
    const int j = blockIdx.x * 4 + wave;          // 0..1023

    const float4* x4 = (const float4*)(ws + WS_X);
    float4 xreg[4];
#pragma unroll
    for (int k = 0; k < 4; ++k) xreg[k] = x4[lane + k * 64];

    float d[3];
#pragma unroll
    for (int g = 0; g < 3; ++g) {
        const float4* r4 = (const float4*)(Wih + (size_t)(g * H + j) * H);
        float acc = 0.f;
#pragma unroll
        for (int k = 0; k < 4; ++k) {
            float4 a = r4[lane + k * 64];
            acc += a.x * xreg[k].x + a.y * xreg[k].y + a.z * xreg[k].z + a.w * xreg[k].w;
        }
        d[g] = waveReduceSum(acc);
    }
    if (lane == 0) {
        float i_r = d[0] + bih[j];
        float i_z = d[1] + bih[H + j];
        float i_n = d[2] + bih[2 * H + j];
        float h_r = ws[WS_GH + j];
        float h_z = ws[WS_GH + H + j];
        float h_n = ws[WS_GH + 2 * H + j];
        float hj  = hidden[j];
        float rg = 1.f / (1.f + expf(-(i_r + h_r)));
        float zg = 1.f / (1.f + expf(-(i_z + h_z)));
        float ng = tanhf(i_n + rg * h_n);
        float hn = (1.f - zg) * ng + zg * hj;
        ws[WS_HNEW + j] = hn;
        out[(size_t)V + j] = hn;                  // h_new output
    }
}

// ---------------- k4: logits = out_W·h_new + out_b  (+ per-block online m,s)
// 2 rows per wave-iteration; biases hoisted ahead of the reduce chain.
__global__ __launch_bounds__(256) void k4_logits(
    const float* __restrict__ out_W, const float* __restrict__ out_b,
    float* __restrict__ ws, float* __restrict__ out)
{
    __shared__ float s_m[4], s_s[4];
    const int t = threadIdx.x;
    const int wave = t >> 6, lane = t & 63;
    const int gw = blockIdx.x * 4 + wave;
    const int NW = NBLK4 * 4;

    const float4* h4 = (const float4*)(ws + WS_HNEW);
    float4 hreg[4];
#pragma unroll
    for (int k = 0; k < 4; ++k) hreg[k] = h4[lane + k * 64];

    float m = -INFINITY, s = 0.f;
    for (int v = gw * 2; v < V; v += NW * 2) {
        const int v1 = v + 1;
        const float4* r4a = (const float4*)(out_W + (size_t)v * H);
        float b0 = out_b[v];                      // issue early, off critical path
        float acc0 = 0.f, acc1 = 0.f;
        float b1 = 0.f;
        if (v1 < V) {
            const float4* r4b = (const float4*)(out_W + (size_t)v1 * H);
            b1 = out_b[v1];
#pragma unroll
            for (int k = 0; k < 4; ++k) {
                float4 a = r4a[lane + k * 64];
                float4 b = r4b[lane + k * 64];
                acc0 += a.x * hreg[k].x + a.y * hreg[k].y + a.z * hreg[k].z + a.w * hreg[k].w;
                acc1 += b.x * hreg[k].x + b.y * hreg[k].y + b.z * hreg[k].z + b.w * hreg[k].w;
            }
        } else {
#pragma unroll
            for (int k = 0; k < 4; ++k) {
                float4 a = r4a[lane + k * 64];
                acc0 += a.x * hreg[k].x + a.y * hreg[k].y + a.z * hreg[k].z + a.w * hreg[k].w;
            }
        }
        acc0 = waveReduceSum(acc0);
        acc1 = waveReduceSum(acc1);
        float logit0 = acc0 + b0;
        if (lane == 0) out[v] = logit0;
        float mn = fmaxf(m, logit0);
        s = s * expf(m - mn) + expf(logit0 - mn);
        m = mn;
        if (v1 < V) {
            float logit1 = acc1 + b1;
            if (lane == 0) out[v1] = logit1;
            mn = fmaxf(m, logit1);
            s = s * expf(m - mn) + expf(logit1 - mn);
            m = mn;
        }
    }
    if (lane == 0) { s_m[wave] = m; s_s[wave] = s; }
    __syncthreads();
    if (t == 0) {
        float M = s_m[0], S = s_s[0];
#pragma unroll
        for (int w = 1; w < 4; ++w) {
            float m2 = s_m[w], s2 = s_s[w];
            float Mn = fmaxf(M, m2);
            S = S * expf(M - Mn) + s2 * expf(m2 - Mn);
            M = Mn;
        }
        ws[WS_PAIRS + blockIdx.x * 2]     = M;
        ws[WS_PAIRS + blockIdx.x * 2 + 1] = S;
    }
}

// ---------------- k5: reduce (m,s) pairs -> lse; out[v] -= lse (in place)
__global__ __launch_bounds__(256) void k5_lse_sub(
    float* __restrict__ ws, float* __restrict__ out)
{
    __shared__ float s_m[256], s_s[256];
    const int t = threadIdx.x;
    float M = -INFINITY, S = 0.f;
    for (int i = t; i < NBLK4; i += 256) {
        float m2 = ws[WS_PAIRS + i * 2], s2 = ws[WS_PAIRS + i * 2 + 1];
        float Mn = fmaxf(M, m2);
        S = S * expf(M - Mn) + s2 * expf(m2 - Mn);
        M = Mn;
    }
    s_m[t] = M; s_s[t] = S;
    __syncthreads();
    for (int off = 128; off > 0; off >>= 1) {
        if (t < off) {
            float m2 = s_m[t + off], s2 = s_s[t + off];
            float Mn = fmaxf(s_m[t], m2);
            s_s[t] = s_s[t] * expf(s_m[t] - Mn) + s2 * expf(m2 - Mn);
            s_m[t] = Mn;
        }
        __syncthreads();
    }
    const float lse = s_m[0] + logf(s_s[0]);
    const int n = gridDim.x * 256;
    for (int v = blockIdx.x * 256 + t; v < V; v += n) out[v] -= lse;
}

extern "C" void kernel_launch(void* const* d_in, const int* in_sizes, int n_in,
                              void* d_out, int out_size, void* d_ws, size_t ws_size,
                              hipStream_t stream) {
    const int*   ids    = (const int*)  d_in[0];
    const float* hidden = (const float*)d_in[1];
    const float* enc    = (const float*)d_in[2];
    const float* emb    = (const float*)d_in[3];
    const float* attn_W = (const float*)d_in[4];
    const float* attn_b = (const float*)d_in[5];
    const float* comb_W = (const float*)d_in[6];
    const float* comb_b = (const float*)d_in[7];
    const float* Wih    = (const float*)d_in[8];
    const float* Whh    = (const float*)d_in[9];
    const float* bih    = (const float*)d_in[10];
    const float* bhh    = (const float*)d_in[11];
    const float* out_W  = (const float*)d_in[12];
    const float* out_b  = (const float*)d_in[13];
    float* out = (float*)d_out;
    float* ws  = (float*)d_ws;

    hipLaunchKernelGGL(k1_attn,    dim3(1),     dim3(1024), 0, stream,
                       ids, hidden, enc, emb, attn_W, attn_b, ws, out);
    hipLaunchKernelGGL(k2_comb_gh, dim3(1024),  dim3(256),  0, stream,
                       hidden, comb_W, comb_b, Whh, bhh, ws);
    hipLaunchKernelGGL(k3_gru,     dim3(256),   dim3(256),  0, stream,
                       hidden, Wih, bih, ws, out);
    hipLaunchKernelGGL(k4_logits,  dim3(NBLK4), dim3(256),  0, stream,
                       out_W, out_b, ws, out);
    hipLaunchKernelGGL(k5_lse_sub, dim3(128),   dim3(256),  0, stream,
                       ws, out);
}